// Round 1
// baseline (3900.659 us; speedup 1.0000x reference)
//
#include <hip/hip_runtime.h>

#define NBATCH 32
#define NPTS   16384
#define IN_F   2
#define HID    256
#define OUT_F  3
#define W_TOT  197888   // 2*256 + 3*256*256 + 256*3
#define B_TOT  1027     // 4*256 + 3
#define PTILE  64
#define PAD    4

// out buffer layout (floats):
//   [0)          outputs  32*16384*3 = 1572864
//   [1572864)    coords   32*16384*2 = 1048576
//   [2621440)    w        32*197888  = 6332416
//   [8953856)    b        32*1027    = 32864
//   [8986720)    latent   32*256     = 8192
// total 8994912

__global__ __launch_bounds__(256, 2)
void siren_fwd_fp32(const float* __restrict__ coords,
                    const float* __restrict__ w,
                    const float* __restrict__ b,
                    float* __restrict__ out)
{
    // activations transposed: A[feature][point], padded rows (272B) for writes
    __shared__ float A[HID][PTILE + PAD];

    const int bid   = blockIdx.x;
    const int batch = bid >> 8;      // 256 tiles per batch
    const int tile  = bid & 255;
    const int t     = threadIdx.x;
    const int n0    = tile * PTILE;

    const float* wb = w + (size_t)batch * W_TOT;
    const float* bb = b + (size_t)batch * B_TOT;
    const float2* c2 = (const float2*)(coords + (size_t)(batch * NPTS + n0) * IN_F);

    const float OMEGA = 30.0f;

    // ---- Layer 0: 2 -> 256. Thread t owns output feature o = t. ----
    {
        const float w0 = wb[t * 2 + 0];
        const float w1 = wb[t * 2 + 1];
        const float b0 = bb[t];
        #pragma unroll 4
        for (int p = 0; p < PTILE; ++p) {
            const float2 c = c2[p];
            const float u = fmaf(c.x, w0, fmaf(c.y, w1, b0));
            A[t][p] = sinf(OMEGA * u);
        }
    }
    __syncthreads();

    // ---- Hidden layers: 256 -> 256, x3. Thread t owns output feature t. ----
    for (int li = 0; li < 3; ++li) {
        const float* Wl = wb + 512 + li * 65536 + t * 256;  // this thread's W row
        const float  bo = bb[256 + li * 256 + t];
        float res[PTILE];

        #pragma unroll
        for (int pb = 0; pb < 2; ++pb) {
            float acc[32];
            #pragma unroll
            for (int i = 0; i < 32; ++i) acc[i] = bo;

            for (int k = 0; k < 256; k += 4) {
                const float4 wv = *(const float4*)(Wl + k);
                #pragma unroll
                for (int kk = 0; kk < 4; ++kk) {
                    const float wk = (&wv.x)[kk];
                    const float* ar = &A[k + kk][pb * 32];
                    #pragma unroll
                    for (int i = 0; i < 32; i += 4) {
                        const float4 a4 = *(const float4*)(ar + i);  // broadcast
                        acc[i + 0] = fmaf(a4.x, wk, acc[i + 0]);
                        acc[i + 1] = fmaf(a4.y, wk, acc[i + 1]);
                        acc[i + 2] = fmaf(a4.z, wk, acc[i + 2]);
                        acc[i + 3] = fmaf(a4.w, wk, acc[i + 3]);
                    }
                }
            }
            #pragma unroll
            for (int i = 0; i < 32; ++i)
                res[pb * 32 + i] = sinf(OMEGA * acc[i]);
        }

        __syncthreads();   // everyone done READING A
        #pragma unroll
        for (int p = 0; p < PTILE; p += 4) {
            *(float4*)&A[t][p] = make_float4(res[p], res[p + 1], res[p + 2], res[p + 3]);
        }
        __syncthreads();   // new A visible
    }

    // ---- Layer 4: 256 -> 3. Threads 0..191: o = t>>6, p = t&63. ----
    if (t < 192) {
        const int o = t >> 6;
        const int p = t & 63;
        const float* W4 = wb + 197120 + o * 256;
        float acc = bb[1024 + o];
        for (int k = 0; k < 256; k += 4) {
            const float4 wv = *(const float4*)(W4 + k);
            acc = fmaf(A[k + 0][p], wv.x, acc);
            acc = fmaf(A[k + 1][p], wv.y, acc);
            acc = fmaf(A[k + 2][p], wv.z, acc);
            acc = fmaf(A[k + 3][p], wv.w, acc);
        }
        out[(size_t)(batch * NPTS + n0 + p) * OUT_F + o] = acc;
    }
}

extern "C" void kernel_launch(void* const* d_in, const int* in_sizes, int n_in,
                              void* d_out, int out_size, void* d_ws, size_t ws_size,
                              hipStream_t stream)
{
    const float* coords = (const float*)d_in[0];
    const float* w      = (const float*)d_in[1];
    const float* bvec   = (const float*)d_in[2];
    const float* latent = (const float*)d_in[3];
    float* out = (float*)d_out;

    dim3 grid(NBATCH * (NPTS / PTILE));   // 8192 blocks
    siren_fwd_fp32<<<grid, 256, 0, stream>>>(coords, w, bvec, out);

    // passthrough outputs 1..4
    hipMemcpyAsync(out + 1572864, coords, (size_t)1048576 * sizeof(float),
                   hipMemcpyDeviceToDevice, stream);
    hipMemcpyAsync(out + 2621440, w,      (size_t)6332416 * sizeof(float),
                   hipMemcpyDeviceToDevice, stream);
    hipMemcpyAsync(out + 8953856, bvec,   (size_t)32864   * sizeof(float),
                   hipMemcpyDeviceToDevice, stream);
    hipMemcpyAsync(out + 8986720, latent, (size_t)8192    * sizeof(float),
                   hipMemcpyDeviceToDevice, stream);
}

// Round 2
// 1150.707 us; speedup vs baseline: 3.3898x; 3.3898x over previous
//
#include <hip/hip_runtime.h>

typedef float f32x4 __attribute__((ext_vector_type(4)));
typedef _Float16 f16x8 __attribute__((ext_vector_type(8)));

#define NBATCH 32
#define NPTS   16384
#define W_TOT  197888
#define B_TOT  1027

// ws layout (halves):
//   [0)         W hi frags, hidden layers: 32 b * 3 l * 65536
//   [6291456)   W lo frags
//   [12582912)  W4 hi frags: 32 b * 8 s * 512
//   total 12713984 halves = 25427968 bytes
#define WLO_OFF 6291456
#define W4_OFF  12582912
#define WS_NEEDED 25427968ull

// out layout (floats)
#define OUT_COORDS 1572864
#define OUT_W      2621440
#define OUT_B      8953856
#define OUT_LAT    8986720

#define SWZH(p) (((p)&7)<<3)   // XOR swizzle in half units (16B blocks)

static __device__ __forceinline__ float fast_sin30(float x) {
    // sin(30*x) = sin(2*pi*t), t = x*30/(2pi), reduced to [-0.5,0.5]
    float t = x * 4.774648292756860f;
    t -= rintf(t);
    float t2 = t * t;
    float p = -0.71812230f;
    p = fmaf(p, t2, 3.81995259f);
    p = fmaf(p, t2, -15.09464257f);
    p = fmaf(p, t2, 42.05869394f);
    p = fmaf(p, t2, -76.70585975f);
    p = fmaf(p, t2, 81.60524928f);
    p = fmaf(p, t2, -41.34170224f);
    p = fmaf(p, t2, 6.28318531f);
    return p * t;
}

static __device__ __forceinline__ unsigned pack2(_Float16 a, _Float16 b) {
    unsigned short ua = __builtin_bit_cast(unsigned short, a);
    unsigned short ub = __builtin_bit_cast(unsigned short, b);
    return (unsigned)ua | ((unsigned)ub << 16);
}
static __device__ __forceinline__ _Float16 lo16(unsigned u) {
    return __builtin_bit_cast(_Float16, (unsigned short)(u & 0xffffu));
}
static __device__ __forceinline__ _Float16 hi16(unsigned u) {
    return __builtin_bit_cast(_Float16, (unsigned short)(u >> 16));
}

union FragU { uint4 u; f16x8 v; };

static __device__ __forceinline__ f16x8 ld_frag(const _Float16* base, int i0, int i1) {
    uint2 q0 = *(const uint2*)(base + i0);
    uint2 q1 = *(const uint2*)(base + i1);
    FragU x; x.u = make_uint4(q0.x, q0.y, q1.x, q1.y);
    return x.v;
}

// ---- pre-kernel: split W into hi/lo fp16 fragments in MFMA B-layout ----
// frag element order: [batch][layer][s][ntile][lane][r]
// col = ntile*16 + (lane&15); k = s*32 + 4*(lane>>4) + (r&3) + 16*(r>>2)
__global__ void make_wfrags(const float* __restrict__ w, _Float16* __restrict__ wf) {
    int idx = blockIdx.x * 256 + threadIdx.x;
    if (idx < 6291456) {
        int batch = idx / 196608;
        int rem   = idx - batch * 196608;
        int layer = rem >> 16;
        int rem2  = rem & 65535;
        int s     = rem2 >> 13;
        int rem3  = rem2 & 8191;
        int ntile = rem3 >> 9;
        int rem4  = rem3 & 511;
        int lane  = rem4 >> 3, r = rem4 & 7;
        int col = ntile * 16 + (lane & 15);
        int k   = s * 32 + 4 * (lane >> 4) + (r & 3) + 16 * (r >> 2);
        float v = w[(size_t)batch * W_TOT + 512 + layer * 65536 + col * 256 + k];
        _Float16 h = (_Float16)v;
        wf[idx] = h;
        wf[WLO_OFF + idx] = (_Float16)(v - (float)h);
    } else if (idx < 6291456 + 131072) {
        int i4 = idx - 6291456;
        int batch = i4 >> 12;
        int rem   = i4 & 4095;
        int s     = rem >> 9;
        int rem2  = rem & 511;
        int lane  = rem2 >> 3, r = rem2 & 7;
        int col = lane & 15;
        int k   = s * 32 + 4 * (lane >> 4) + (r & 3) + 16 * (r >> 2);
        float v = (col < 3) ? w[(size_t)batch * W_TOT + 197120 + col * 256 + k] : 0.0f;
        wf[W4_OFF + i4] = (_Float16)v;
    }
}

// ---- main kernel: fused SIREN, 64 points per block, MFMA hidden layers ----
__global__ __launch_bounds__(256, 2)
void siren_mfma(const float* __restrict__ coords,
                const float* __restrict__ w,
                const float* __restrict__ b,
                const _Float16* __restrict__ wf,
                float* __restrict__ out)
{
    __shared__ _Float16 Ahi[64 * 256];
    __shared__ _Float16 Alo[64 * 256];

    const int bid = blockIdx.x, batch = bid >> 8, tile = bid & 255, n0 = tile * 64;
    const int t = threadIdx.x, wave = t >> 6, lane = t & 63;
    const int row = lane & 15, g = lane >> 4;

    const float* wb = w + (size_t)batch * W_TOT;
    const float* bb = b + (size_t)batch * B_TOT;

    // ---- layer 0: 2 -> 256 (VALU) ----
    {
        int p = t >> 2, fb = (t & 3) * 64;
        float2 c = ((const float2*)coords)[(size_t)batch * NPTS + n0 + p];
        int swz = SWZH(p);
        #pragma unroll 8
        for (int j = 0; j < 64; j += 2) {
            int f = fb + j;
            float4 wv = *(const float4*)(wb + 2 * f);
            float b0 = bb[f], b1 = bb[f + 1];
            float s0 = fast_sin30(fmaf(c.x, wv.x, fmaf(c.y, wv.y, b0)));
            float s1 = fast_sin30(fmaf(c.x, wv.z, fmaf(c.y, wv.w, b1)));
            _Float16 h0 = (_Float16)s0, h1 = (_Float16)s1;
            _Float16 l0 = (_Float16)(s0 - (float)h0), l1 = (_Float16)(s1 - (float)h1);
            int idx = (p * 256 + f) ^ swz;
            *(unsigned*)&Ahi[idx] = pack2(h0, h1);
            *(unsigned*)&Alo[idx] = pack2(l0, l1);
        }
    }

    // ---- hidden layers: 256 -> 256, MFMA fp16-split 3-pass ----
    for (int li = 0; li < 3; ++li) {
        __syncthreads();   // A writes visible
        f32x4 acc[4][4] = {};
        const _Float16* whf = wf + (size_t)(batch * 3 + li) * 65536;

        for (int s = 0; s < 8; ++s) {
            f16x8 ah[4], al[4];
            #pragma unroll
            for (int mt = 0; mt < 4; ++mt) {
                int p = mt * 16 + row;
                int base = p * 256 + s * 32 + 4 * g;
                int sw = SWZH(p);
                ah[mt] = ld_frag(Ahi, base ^ sw, (base + 16) ^ sw);
                al[mt] = ld_frag(Alo, base ^ sw, (base + 16) ^ sw);
            }
            #pragma unroll
            for (int nt = 0; nt < 4; ++nt) {
                const _Float16* pb = whf + s * 8192 + (wave * 4 + nt) * 512 + lane * 8;
                f16x8 bh = *(const f16x8*)pb;
                f16x8 bl = *(const f16x8*)(pb + WLO_OFF);
                #pragma unroll
                for (int mt = 0; mt < 4; ++mt) {
                    acc[mt][nt] = __builtin_amdgcn_mfma_f32_16x16x32_f16(ah[mt], bh, acc[mt][nt], 0, 0, 0);
                    acc[mt][nt] = __builtin_amdgcn_mfma_f32_16x16x32_f16(ah[mt], bl, acc[mt][nt], 0, 0, 0);
                    acc[mt][nt] = __builtin_amdgcn_mfma_f32_16x16x32_f16(al[mt], bh, acc[mt][nt], 0, 0, 0);
                }
            }
        }

        // bias + sin + fp16 split (registers only)
        unsigned spk[4][4][4];
        #pragma unroll
        for (int nt = 0; nt < 4; ++nt) {
            float bias = bb[256 + li * 256 + wave * 64 + nt * 16 + row];
            #pragma unroll
            for (int mt = 0; mt < 4; ++mt) {
                #pragma unroll
                for (int j = 0; j < 4; ++j) {
                    float v = fast_sin30(acc[mt][nt][j] + bias);
                    _Float16 h = (_Float16)v;
                    _Float16 l = (_Float16)(v - (float)h);
                    spk[mt][nt][j] = pack2(h, l);
                }
            }
        }

        __syncthreads();   // all reads of A done
        #pragma unroll
        for (int mt = 0; mt < 4; ++mt) {
            #pragma unroll
            for (int j = 0; j < 4; ++j) {
                int p = mt * 16 + g * 4 + j;
                int sw = SWZH(p);
                int base = p * 256 + wave * 64 + row;
                #pragma unroll
                for (int nt = 0; nt < 4; ++nt) {
                    int idx = (base + nt * 16) ^ sw;
                    Ahi[idx] = lo16(spk[mt][nt][j]);
                    Alo[idx] = hi16(spk[mt][nt][j]);
                }
            }
        }
    }
    __syncthreads();

    // ---- layer 4: 256 -> 3 via MFMA (hi only), wave w owns m-tile w ----
    {
        f32x4 acc = {};
        const int mt = wave;
        const _Float16* w4 = wf + W4_OFF + batch * 4096;
        for (int s = 0; s < 8; ++s) {
            int p = mt * 16 + row;
            int base = p * 256 + s * 32 + 4 * g;
            int sw = SWZH(p);
            f16x8 ah = ld_frag(Ahi, base ^ sw, (base + 16) ^ sw);
            f16x8 b4 = *(const f16x8*)(w4 + s * 512 + lane * 8);
            acc = __builtin_amdgcn_mfma_f32_16x16x32_f16(ah, b4, acc, 0, 0, 0);
        }
        if (row < 3) {
            float bias = bb[1024 + row];
            #pragma unroll
            for (int j = 0; j < 4; ++j) {
                int p = mt * 16 + g * 4 + j;
                out[((size_t)batch * NPTS + n0 + p) * 3 + row] = acc[j] + bias;
            }
        }
    }
}

// ---- fallback fp32 kernel (used only if ws too small) ----
__global__ __launch_bounds__(256, 2)
void siren_fwd_fp32(const float* __restrict__ coords,
                    const float* __restrict__ w,
                    const float* __restrict__ b,
                    float* __restrict__ out)
{
    __shared__ float A[256][64 + 4];
    const int bid = blockIdx.x, batch = bid >> 8, tile = bid & 255;
    const int t = threadIdx.x, n0 = tile * 64;
    const float* wb = w + (size_t)batch * W_TOT;
    const float* bb = b + (size_t)batch * B_TOT;
    const float2* c2 = (const float2*)(coords + (size_t)(batch * NPTS + n0) * 2);
    {
        const float w0 = wb[t * 2 + 0], w1 = wb[t * 2 + 1], b0 = bb[t];
        for (int p = 0; p < 64; ++p) {
            const float2 c = c2[p];
            A[t][p] = fast_sin30(fmaf(c.x, w0, fmaf(c.y, w1, b0)));
        }
    }
    __syncthreads();
    for (int li = 0; li < 3; ++li) {
        const float* Wl = wb + 512 + li * 65536 + t * 256;
        const float bo = bb[256 + li * 256 + t];
        float res[64];
        for (int pb = 0; pb < 2; ++pb) {
            float acc[32];
            #pragma unroll
            for (int i = 0; i < 32; ++i) acc[i] = bo;
            for (int k = 0; k < 256; k += 4) {
                const float4 wv = *(const float4*)(Wl + k);
                #pragma unroll
                for (int kk = 0; kk < 4; ++kk) {
                    const float wk = (&wv.x)[kk];
                    const float* ar = &A[k + kk][pb * 32];
                    #pragma unroll
                    for (int i = 0; i < 32; i += 4) {
                        const float4 a4 = *(const float4*)(ar + i);
                        acc[i + 0] = fmaf(a4.x, wk, acc[i + 0]);
                        acc[i + 1] = fmaf(a4.y, wk, acc[i + 1]);
                        acc[i + 2] = fmaf(a4.z, wk, acc[i + 2]);
                        acc[i + 3] = fmaf(a4.w, wk, acc[i + 3]);
                    }
                }
            }
            #pragma unroll
            for (int i = 0; i < 32; ++i) res[pb * 32 + i] = fast_sin30(acc[i]);
        }
        __syncthreads();
        for (int p = 0; p < 64; p += 4)
            *(float4*)&A[t][p] = make_float4(res[p], res[p+1], res[p+2], res[p+3]);
        __syncthreads();
    }
    if (t < 192) {
        const int o = t >> 6, p = t & 63;
        const float* W4 = wb + 197120 + o * 256;
        float acc = bb[1024 + o];
        for (int k = 0; k < 256; k += 4) {
            const float4 wv = *(const float4*)(W4 + k);
            acc = fmaf(A[k+0][p], wv.x, acc);
            acc = fmaf(A[k+1][p], wv.y, acc);
            acc = fmaf(A[k+2][p], wv.z, acc);
            acc = fmaf(A[k+3][p], wv.w, acc);
        }
        out[(size_t)(batch * NPTS + n0 + p) * 3 + o] = acc;
    }
}

extern "C" void kernel_launch(void* const* d_in, const int* in_sizes, int n_in,
                              void* d_out, int out_size, void* d_ws, size_t ws_size,
                              hipStream_t stream)
{
    const float* coords = (const float*)d_in[0];
    const float* w      = (const float*)d_in[1];
    const float* bvec   = (const float*)d_in[2];
    const float* latent = (const float*)d_in[3];
    float* out = (float*)d_out;

    if (ws_size >= WS_NEEDED) {
        _Float16* wf = (_Float16*)d_ws;
        make_wfrags<<<25088, 256, 0, stream>>>(w, wf);
        siren_mfma<<<NBATCH * (NPTS / 64), 256, 0, stream>>>(coords, w, bvec, wf, out);
    } else {
        siren_fwd_fp32<<<NBATCH * (NPTS / 64), 256, 0, stream>>>(coords, w, bvec, out);
    }

    hipMemcpyAsync(out + OUT_COORDS, coords, (size_t)1048576 * sizeof(float),
                   hipMemcpyDeviceToDevice, stream);
    hipMemcpyAsync(out + OUT_W,      w,      (size_t)6332416 * sizeof(float),
                   hipMemcpyDeviceToDevice, stream);
    hipMemcpyAsync(out + OUT_B,      bvec,   (size_t)32864   * sizeof(float),
                   hipMemcpyDeviceToDevice, stream);
    hipMemcpyAsync(out + OUT_LAT,    latent, (size_t)8192    * sizeof(float),
                   hipMemcpyDeviceToDevice, stream);
}